// Round 1
// baseline (368.506 us; speedup 1.0000x reference)
//
#include <hip/hip_runtime.h>
#include <math.h>

// RoPE "rotation matrix * x" — but it's an ELEMENTWISE product, and R is
// 2x2-block-diagonal: out[b,i,j] = 0 except j in {i&~1, (i&~1)+1}.
// So this is a streaming-store kernel: write 256 MiB of mostly zeros,
// patch 2 entries per row with {c,-s,s,c} * x. Read traffic ~0.
//
// D=2048, B=16, BASE=10000, m is a runtime int input.

constexpr int D = 2048;
constexpr int B = 16;
constexpr long long TOTAL4 = (long long)B * D * D / 4;  // 16,777,216 float4s

__global__ __launch_bounds__(256) void rope_block_diag_kernel(
        const float* __restrict__ x, const int* __restrict__ m_ptr,
        float* __restrict__ out) {
    const long long idx = (long long)blockIdx.x * blockDim.x + threadIdx.x;
    // grid is exact (TOTAL4 / 256), no bounds check needed
    const int col4 = (int)(idx & (D / 4 - 1));        // float4 index in row: 0..511
    const int j0   = col4 << 2;                       // first column of this float4
    const int i    = (int)((idx >> 9) & (D - 1));     // row within the (D,D) matrix

    float4 v = make_float4(0.f, 0.f, 0.f, 0.f);

    // The row's 2x2 block sits at columns c0 = i&~1, c0+1. Both live in the
    // float4 whose j0 == i&~3. Exactly one float4 per row takes this path.
    if (j0 == (i & ~3)) {
        const int m = *m_ptr;
        const int p = i >> 1;                         // pair index, 0..1023
        // ang = m / BASE^(2p/D); compute in double (only ~32K threads do this)
        const double ang = (double)m * exp((-2.0 * (double)p / (double)D) * log(10000.0));
        const float c = (float)cos(ang);
        const float s = (float)sin(ang);

        const float4 xv = ((const float4*)x)[idx];    // same location in x
        const int o = i & 2;                          // offset of c0 within float4: 0 or 2
        const float xa = (o == 0) ? xv.x : xv.z;      // x[b,i,c0]
        const float xb = (o == 0) ? xv.y : xv.w;      // x[b,i,c0+1]
        // even row (i=2p):  [ c, -s ] ;  odd row (i=2p+1): [ s, c ]
        const float va = (i & 1) ? (s * xa) : (c * xa);
        const float vb = (i & 1) ? (c * xb) : (-s * xb);
        if (o == 0) { v.x = va; v.y = vb; }
        else        { v.z = va; v.w = vb; }
    }

    ((float4*)out)[idx] = v;
}

extern "C" void kernel_launch(void* const* d_in, const int* in_sizes, int n_in,
                              void* d_out, int out_size, void* d_ws, size_t ws_size,
                              hipStream_t stream) {
    const float* x     = (const float*)d_in[0];
    const int*   m_ptr = (const int*)d_in[1];
    float*       out   = (float*)d_out;

    const int block = 256;
    const long long grid = TOTAL4 / block;  // 65536 blocks
    rope_block_diag_kernel<<<(unsigned)grid, block, 0, stream>>>(x, m_ptr, out);
}